// Round 2
// 4582.481 us; speedup vs baseline: 1.2031x; 1.2031x over previous
//
#include <hip/hip_runtime.h>
#include <math.h>

#define Bb 4
#define Ls 2048
#define Dd 1024
#define Hh 16
#define HDm 64
#define ML (Bb*Ls)   /* 8192 rows */

typedef double f64x4 __attribute__((ext_vector_type(4)));

// ---------------------------------------------------------------------------
// NT GEMM, fp64 accumulate, fp64 output: C[m,n] = sum_k A[m,k]*B[n,k]
// fp64 needed: logits sigma~1.1e6; argmax vs fp64 reference needs abs logit
// error << top-2 gap; fp32 projections give ~4e3 error -> fail.
// ---------------------------------------------------------------------------
__global__ __launch_bounds__(256) void gemm_nt_f64(
    const float* __restrict__ A, const float* __restrict__ B,
    double* __restrict__ C) {
  const int N = Dd, K = Dd;
  __shared__ float As[64][17];
  __shared__ float Bs[64][17];
  int tid = threadIdx.x;
  int tx = tid & 15, ty = tid >> 4;
  int bm = blockIdx.y * 64, bn = blockIdx.x * 64;
  double acc[4][4];
#pragma unroll
  for (int i = 0; i < 4; i++)
#pragma unroll
    for (int j = 0; j < 4; j++) acc[i][j] = 0.0;

  for (int k0 = 0; k0 < K; k0 += 16) {
#pragma unroll
    for (int i = 0; i < 4; i++) {
      int idx = tid + i * 256;
      int r = idx >> 4, c = idx & 15;
      As[r][c] = A[(size_t)(bm + r) * K + k0 + c];
      Bs[r][c] = B[(size_t)(bn + r) * K + k0 + c];
    }
    __syncthreads();
#pragma unroll
    for (int kk = 0; kk < 16; kk++) {
      double a[4], b[4];
#pragma unroll
      for (int i = 0; i < 4; i++) a[i] = (double)As[ty * 4 + i][kk];
#pragma unroll
      for (int j = 0; j < 4; j++) b[j] = (double)Bs[tx * 4 + j][kk];
#pragma unroll
      for (int i = 0; i < 4; i++)
#pragma unroll
        for (int j = 0; j < 4; j++)
          acc[i][j] = fma(a[i], b[j], acc[i][j]);
    }
    __syncthreads();
  }
#pragma unroll
  for (int i = 0; i < 4; i++) {
    size_t m = (size_t)(bm + ty * 4 + i);
#pragma unroll
    for (int j = 0; j < 4; j++) {
      int n = bn + tx * 4 + j;
      C[m * N + n] = acc[i][j];
    }
  }
}

// ---------------------------------------------------------------------------
// NT GEMM, fp32, optional bias
// ---------------------------------------------------------------------------
__global__ __launch_bounds__(256) void gemm_nt_f32(
    const float* __restrict__ A, const float* __restrict__ B,
    const float* __restrict__ bias, float* __restrict__ C) {
  const int N = Dd, K = Dd;
  __shared__ float As[64][17];
  __shared__ float Bs[64][17];
  int tid = threadIdx.x;
  int tx = tid & 15, ty = tid >> 4;
  int bm = blockIdx.y * 64, bn = blockIdx.x * 64;
  float acc[4][4];
#pragma unroll
  for (int i = 0; i < 4; i++)
#pragma unroll
    for (int j = 0; j < 4; j++) acc[i][j] = 0.0f;

  for (int k0 = 0; k0 < K; k0 += 16) {
#pragma unroll
    for (int i = 0; i < 4; i++) {
      int idx = tid + i * 256;
      int r = idx >> 4, c = idx & 15;
      As[r][c] = A[(size_t)(bm + r) * K + k0 + c];
      Bs[r][c] = B[(size_t)(bn + r) * K + k0 + c];
    }
    __syncthreads();
#pragma unroll
    for (int kk = 0; kk < 16; kk++) {
      float a[4], b[4];
#pragma unroll
      for (int i = 0; i < 4; i++) a[i] = As[ty * 4 + i][kk];
#pragma unroll
      for (int j = 0; j < 4; j++) b[j] = Bs[tx * 4 + j][kk];
#pragma unroll
      for (int i = 0; i < 4; i++)
#pragma unroll
        for (int j = 0; j < 4; j++)
          acc[i][j] = fmaf(a[i], b[j], acc[i][j]);
    }
    __syncthreads();
  }
#pragma unroll
  for (int i = 0; i < 4; i++) {
    size_t m = (size_t)(bm + ty * 4 + i);
#pragma unroll
    for (int j = 0; j < 4; j++) {
      int n = bn + tx * 4 + j;
      float v = acc[i][j];
      if (bias) v += bias[n];
      C[m * N + n] = v;
    }
  }
}

// ---------------------------------------------------------------------------
// One-sweep flash attention, v4: fp64 MFMA QK^T (v3 with corrected D layout).
// v3 FAILED (absmax 7968): assumed f32-style D layout row=4*(l>>4)+reg.
// v_mfma_f64_16x16x4f64 actually has group_size=1 (CK xdlops_gemm traits,
// Tensile MIOutputVectorWidth=1): D row = 4*reg + (lane>>4), col = lane&15.
// Pure relabel: softmax reduce (over lrow lanes, fixed (d,lk)) was already
// within one true row; Ps slot 4*lk+d now carries row 4d+lk and the PV
// float4 read at 4*lk recovers exactly the reader's softmax rows. Only the
// three `row =` expressions change (4*lk+d -> 4*d+lk).
//  - Q A-fragments register-resident (lane holds Q[16w+(l&15)][4t+(l>>4)]).
//  - QK^T: 2 quadrants x 16 k-steps = 32 mfma + 32 ds_read_b64 / wave-tile
//    (v2 had 128 ds_read_b128); fp64 work moves to the matrix pipe.
//  - Softmax: float-rounded running ref, BIT-compatible with v2.
//  - PV via per-wave P^T LDS buffer (float4 broadcast reads), wave-internal
//    in-order ds, no barrier.
// LDS: Ks 16896 + Vs 8704 + Ps 10240 = 35840 B -> 4 blocks/CU.
// ---------------------------------------------------------------------------
__global__ __launch_bounds__(256) void attn_flash(
    double* __restrict__ Qd, const double* __restrict__ Kd,
    const float* __restrict__ Vf, float* __restrict__ attn,
    float* __restrict__ O) {
  __shared__ double Ks[32 * 66];
  __shared__ float  Vs[32 * 68];
  __shared__ float  Ps[4][32 * 20];   // per-wave P^T: [col 0..31][slot 0..15]

  const int tid = threadIdx.x;
  const int lane = tid & 63;
  const int w = tid >> 6;             // wave 0..3 -> q-row strip 16w
  const int lrow = lane & 15;         // A-row / B,D-col index
  const int lk = lane >> 4;           // k index / D row low bits
  const int blk = blockIdx.x;
  const int qt = blk & 31;            // 32 q-tiles of 64 rows
  const int h = (blk >> 5) & 15;
  const int b = blk >> 9;
  const int l0 = qt * 64;

  const double* Qg = Qd + ((size_t)(b * Ls + l0)) * Dd + h * HDm;
  const double* Kg = Kd + ((size_t)b * Ls) * Dd + h * HDm;
  const float*  Vg = Vf + ((size_t)b * Ls) * Dd + h * HDm;
  float* aout = attn + ((size_t)((b * Hh + h) * Ls + l0)) * Ls;

  // Q fragments: lane holds Q[16w+lrow][4t+lk] for t=0..15 (whole sweep)
  double qreg[16];
#pragma unroll
  for (int t = 0; t < 16; t++)
    qreg[t] = Qg[(size_t)(16 * w + lrow) * Dd + 4 * t + lk];

  double mref[4], sacc[4];
  float Oacc[4][4];
#pragma unroll
  for (int d = 0; d < 4; d++) {
    mref[d] = -INFINITY;
    sacc[d] = 0.0;
#pragma unroll
    for (int j = 0; j < 4; j++) Oacc[d][j] = 0.0f;
  }

  for (int kt = 0; kt < 64; kt++) {
    __syncthreads();  // prior tile's readers done
#pragma unroll
    for (int it = 0; it < 4; it++) {
      int idx = tid + it * 256;
      int r = idx >> 5, c2 = idx & 31;
      double2 kv = *(const double2*)(Kg + (size_t)(kt * 32 + r) * Dd + c2 * 2);
      *(double2*)(&Ks[r * 66 + c2 * 2]) = kv;
      float2 vv2 = *(const float2*)(Vg + (size_t)(kt * 32 + r) * Dd + c2 * 2);
      *(float2*)(&Vs[r * 68 + c2 * 2]) = vv2;
    }
    __syncthreads();

    // QK^T: E[r][c] = sum_k Q[r][k] K[c][k]; quadrant 0: keys 0-15, 1: 16-31
    f64x4 acc0 = {0.0, 0.0, 0.0, 0.0};
    f64x4 acc1 = {0.0, 0.0, 0.0, 0.0};
#pragma unroll
    for (int t = 0; t < 16; t++) {
      double b0 = Ks[lrow * 66 + 4 * t + lk];
      double b1 = Ks[(16 + lrow) * 66 + 4 * t + lk];
      acc0 = __builtin_amdgcn_mfma_f64_16x16x4f64(qreg[t], b0, acc0, 0, 0, 0);
      acc1 = __builtin_amdgcn_mfma_f64_16x16x4f64(qreg[t], b1, acc1, 0, 0, 0);
    }

    // online softmax per owned row: acc[d] is row 4*d + lk (f64 D layout),
    // col lrow (acc0) / 16+lrow (acc1)
    float fac[4], pP0[4], pP1[4];
#pragma unroll
    for (int d = 0; d < 4; d++) {
      double e0 = acc0[d] * 0.125;
      double e1 = acc1[d] * 0.125;
      float tmf = fmaxf((float)e0, (float)e1);
#pragma unroll
      for (int m = 1; m < 16; m <<= 1) tmf = fmaxf(tmf, __shfl_xor(tmf, m));
      double mo = mref[d];
      float ref_f = fmaxf((float)mo, tmf);   // float-rounded running ref
      double ref = (double)ref_f;
      float p0 = expf((float)(e0 - ref));
      float p1 = expf((float)(e1 - ref));
      double ts = (double)p0 + (double)p1;
#pragma unroll
      for (int m = 1; m < 16; m <<= 1) ts += __shfl_xor(ts, m);
      float factor = expf((float)(mo - ref));  // <= 1
      sacc[d] = sacc[d] * (double)factor + ts;
      mref[d] = ref;
      fac[d] = factor;
      pP0[d] = p0;
      pP1[d] = p1;
      int row = 16 * w + 4 * d + lk;
      aout[(size_t)row * Ls + kt * 32 + lrow] = p0;
      aout[(size_t)row * Ls + kt * 32 + 16 + lrow] = p1;
      if (lrow == 0) {  // stash per-(row,tile) ref in dead Qd slice
        float* mrow = (float*)(Qd + ((size_t)(b * Ls + l0 + row)) * Dd + h * HDm);
        mrow[kt] = ref_f;
      }
    }

    // P^T to per-wave LDS: slot 4*lk+d holds row 4*d+lk of col lrow (/+16);
    // reader's float4 at 4*lk recovers its own softmax rows 4*d+lk.
    *(float4*)(&Ps[w][lrow * 20 + 4 * lk]) =
        make_float4(pP0[0], pP0[1], pP0[2], pP0[3]);
    *(float4*)(&Ps[w][(16 + lrow) * 20 + 4 * lk]) =
        make_float4(pP1[0], pP1[1], pP1[2], pP1[3]);

#pragma unroll
    for (int d = 0; d < 4; d++)
#pragma unroll
      for (int j = 0; j < 4; j++) Oacc[d][j] *= fac[d];

    // PV: lane owns rows 4*d+lk x dims 4*lrow+j; p broadcast from Ps
#pragma unroll
    for (int t = 0; t < 32; t++) {
      float4 pb = *(const float4*)(&Ps[w][t * 20 + 4 * lk]);
      float4 vv = *(const float4*)(&Vs[t * 68 + lrow * 4]);
      Oacc[0][0] = fmaf(pb.x, vv.x, Oacc[0][0]);
      Oacc[0][1] = fmaf(pb.x, vv.y, Oacc[0][1]);
      Oacc[0][2] = fmaf(pb.x, vv.z, Oacc[0][2]);
      Oacc[0][3] = fmaf(pb.x, vv.w, Oacc[0][3]);
      Oacc[1][0] = fmaf(pb.y, vv.x, Oacc[1][0]);
      Oacc[1][1] = fmaf(pb.y, vv.y, Oacc[1][1]);
      Oacc[1][2] = fmaf(pb.y, vv.z, Oacc[1][2]);
      Oacc[1][3] = fmaf(pb.y, vv.w, Oacc[1][3]);
      Oacc[2][0] = fmaf(pb.z, vv.x, Oacc[2][0]);
      Oacc[2][1] = fmaf(pb.z, vv.y, Oacc[2][1]);
      Oacc[2][2] = fmaf(pb.z, vv.z, Oacc[2][2]);
      Oacc[2][3] = fmaf(pb.z, vv.w, Oacc[2][3]);
      Oacc[3][0] = fmaf(pb.w, vv.x, Oacc[3][0]);
      Oacc[3][1] = fmaf(pb.w, vv.y, Oacc[3][1]);
      Oacc[3][2] = fmaf(pb.w, vv.z, Oacc[3][2]);
      Oacc[3][3] = fmaf(pb.w, vv.w, Oacc[3][3]);
    }
  }

  // epilogue: normalize O, stash final ref + sum per row (row = 4*d + lk)
#pragma unroll
  for (int d = 0; d < 4; d++) {
    int row = 16 * w + 4 * d + lk;
    float sv = (float)(1.0 / sacc[d]);
    float4 ov = make_float4(Oacc[d][0] * sv, Oacc[d][1] * sv,
                            Oacc[d][2] * sv, Oacc[d][3] * sv);
    *(float4*)(O + ((size_t)(b * Ls + l0 + row)) * Dd + h * HDm + lrow * 4) = ov;
    if (lrow == 0) {
      float* mrow = (float*)(Qd + ((size_t)(b * Ls + l0 + row)) * Dd + h * HDm);
      mrow[64] = (float)mref[d];
      *(double*)(mrow + 66) = sacc[d];
    }
  }
}

// ---------------------------------------------------------------------------
// Rescale: p = p~ * exp(ref_t - ref_final) / s. One block per attention row.
// ---------------------------------------------------------------------------
__global__ __launch_bounds__(256) void attn_scale(
    float* __restrict__ attn, const double* __restrict__ Qd) {
  int R = blockIdx.x;                 // 0..131071: ((b*Hh+h)*Ls + l)
  int b = R >> 15;
  int rem = R & 32767;
  int h = rem >> 11;
  int l = rem & 2047;
  const float* mrow = (const float*)(Qd + ((size_t)(b * Ls + l)) * Dd + h * HDm);
  int tid = threadIdx.x;
  int kt = tid >> 2;                  // 8 cols per thread, within one 32-col tile
  double mt = (double)mrow[kt];
  double mf = (double)mrow[64];
  double s = *(const double*)(mrow + 66);
  float sc = (float)(exp(mt - mf) / s);
  float4* ap = (float4*)(attn + (size_t)R * Ls + tid * 8);
  float4 a0 = ap[0], a1 = ap[1];
  a0.x *= sc; a0.y *= sc; a0.z *= sc; a0.w *= sc;
  a1.x *= sc; a1.y *= sc; a1.z *= sc; a1.w *= sc;
  ap[0] = a0; ap[1] = a1;
}

// ---------------------------------------------------------------------------
extern "C" void kernel_launch(void* const* d_in, const int* in_sizes, int n_in,
                              void* d_out, int out_size, void* d_ws, size_t ws_size,
                              hipStream_t stream) {
  const float* query = (const float*)d_in[0];
  const float* key   = (const float*)d_in[1];
  const float* value = (const float*)d_in[2];
  const float* Wq    = (const float*)d_in[3];
  const float* Wk    = (const float*)d_in[4];
  const float* Wv    = (const float*)d_in[5];
  const float* Wo    = (const float*)d_in[6];
  const float* bo    = (const float*)d_in[7];

  float* out0 = (float*)d_out;            // [B,L,D]
  float* attn = out0 + (size_t)ML * Dd;   // [B,H,L,L]

  // ws: Qd (64MB f64) | Kd (64MB f64) | Vf (32MB f32) | Of (32MB f32)
  char* ws = (char*)d_ws;
  double* Qd = (double*)ws;
  double* Kd = (double*)(ws + (size_t)ML * Dd * 8);
  float*  Vf = (float*)(ws + (size_t)ML * Dd * 16);
  float*  Of = (float*)(ws + (size_t)ML * Dd * 16 + (size_t)ML * Dd * 4);

  dim3 gemm_grid(Dd / 64, ML / 64);
  gemm_nt_f64<<<gemm_grid, 256, 0, stream>>>(query, Wq, Qd);
  gemm_nt_f64<<<gemm_grid, 256, 0, stream>>>(key,   Wk, Kd);
  gemm_nt_f32<<<gemm_grid, 256, 0, stream>>>(value, Wv, nullptr, Vf);

  attn_flash<<<Bb * Hh * (Ls / 64), 256, 0, stream>>>(Qd, Kd, Vf, attn, Of);
  attn_scale<<<Bb * Hh * Ls, 256, 0, stream>>>(attn, Qd);

  gemm_nt_f32<<<gemm_grid, 256, 0, stream>>>(Of, Wo, bo, out0);
}